// Round 1
// 3188.214 us; speedup vs baseline: 1.0709x; 1.0709x over previous
//
#include <hip/hip_runtime.h>
#include <math.h>

#define NB      8      // batch rows per workgroup in passA/passB
#define NBC     2      // batch rows per workgroup in combine (more parallelism)
#define CHUNKS  64     // time chunks for the parallel linear scan (L = T/CHUNKS = 16)
#define LIM     0x1p100f
#define RESCALE_THRESH 0x1p44f
#define SCL_DN  0x1p-40f

// ---------------------------------------------------------------------------
// Generic tiled fp32 GEMM: C = A@B. A:[M,512], B:[512,512], C:[M,512].
// BM=BN=64, BK=16, 256 threads, 4x4 microtile. Used for U=X@K and R^L powers.
// ---------------------------------------------------------------------------
#define BM 64
#define BN 64
#define BK 16

__global__ __launch_bounds__(256) void gemm_xk(const float* __restrict__ A,
                                               const float* __restrict__ B,
                                               float* __restrict__ C) {
    __shared__ float As[BK][BM + 4];
    __shared__ float Bs[BK][BN];

    const int tid  = threadIdx.x;
    const int col0 = blockIdx.x * BN;
    const int row0 = blockIdx.y * BM;

    const int tx = tid & 15;
    const int ty = tid >> 4;

    const int am = tid >> 2;
    const int ak = (tid & 3) << 2;
    const int bk  = tid >> 4;
    const int bn4 = (tid & 15) << 2;

    float acc[4][4] = {{0.f,0.f,0.f,0.f},{0.f,0.f,0.f,0.f},
                       {0.f,0.f,0.f,0.f},{0.f,0.f,0.f,0.f}};

    for (int k0 = 0; k0 < 512; k0 += BK) {
        float4 av = *(const float4*)(A + (size_t)(row0 + am) * 512 + (k0 + ak));
        float4 bv = *(const float4*)(B + (size_t)(k0 + bk) * 512 + (col0 + bn4));
        __syncthreads();
        As[ak + 0][am] = av.x;
        As[ak + 1][am] = av.y;
        As[ak + 2][am] = av.z;
        As[ak + 3][am] = av.w;
        *(float4*)&Bs[bk][bn4] = bv;
        __syncthreads();
#pragma unroll
        for (int k = 0; k < BK; ++k) {
            float4 a4 = *(const float4*)&As[k][ty << 2];
            float4 b4 = *(const float4*)&Bs[k][tx << 2];
            float ar[4] = {a4.x, a4.y, a4.z, a4.w};
            float br[4] = {b4.x, b4.y, b4.z, b4.w};
#pragma unroll
            for (int i = 0; i < 4; ++i)
#pragma unroll
                for (int j = 0; j < 4; ++j)
                    acc[i][j] = fmaf(ar[i], br[j], acc[i][j]);
        }
    }

#pragma unroll
    for (int i = 0; i < 4; ++i) {
        float4 v = make_float4(acc[i][0], acc[i][1], acc[i][2], acc[i][3]);
        *(float4*)(C + (size_t)(row0 + (ty << 2) + i) * 512 + col0 + (tx << 2)) = v;
    }
}

// ---------------------------------------------------------------------------
// Pass A: per (batch-group g, chunk c), run the local recurrence from ZERO
// state over the chunk, store only the final state y_end(c).
//   y_t = u_t + y_{t-1} @ R   (y_{t0-1} = 0)
// Thread j owns column j for all NB rows (R column reads coalesced across j).
// ---------------------------------------------------------------------------
__global__ __launch_bounds__(512) void passA(const float* __restrict__ U,
                                             const float* __restrict__ R,
                                             float* __restrict__ y_end,
                                             int T, int B) {
    __shared__ float S[2][NB][512];
    const int g  = blockIdx.x;
    const int c  = blockIdx.y;
    const int j  = threadIdx.x;
    const int L  = T / CHUNKS;
    const int t0 = c * L;
    const int r0 = g * NB;

#pragma unroll
    for (int r = 0; r < NB; ++r) S[0][r][j] = 0.f;
    __syncthreads();

    const float* __restrict__ Rc = R + j;
    int cur = 0;

    for (int t = t0; t < t0 + L; ++t) {
        float acc[NB] = {0.f,0.f,0.f,0.f,0.f,0.f,0.f,0.f};
        const float (* __restrict__ Sc)[512] = S[cur];
#pragma unroll 4
        for (int d = 0; d < 512; d += 4) {
            float rv0 = Rc[(size_t)(d + 0) * 512];
            float rv1 = Rc[(size_t)(d + 1) * 512];
            float rv2 = Rc[(size_t)(d + 2) * 512];
            float rv3 = Rc[(size_t)(d + 3) * 512];
#pragma unroll
            for (int r = 0; r < NB; ++r) {
                float4 s4 = *(const float4*)&Sc[r][d];
                acc[r] = fmaf(s4.x, rv0, acc[r]);
                acc[r] = fmaf(s4.y, rv1, acc[r]);
                acc[r] = fmaf(s4.z, rv2, acc[r]);
                acc[r] = fmaf(s4.w, rv3, acc[r]);
            }
        }
#pragma unroll
        for (int r = 0; r < NB; ++r) {
            float u  = U[((size_t)(r0 + r) * T + t) * 512 + j];
            float sn = fminf(fmaxf(u + acc[r], -LIM), LIM);  // NaN-dropping clamp
            S[cur ^ 1][r][j] = sn;
        }
        __syncthreads();
        cur ^= 1;
    }

#pragma unroll
    for (int r = 0; r < NB; ++r)
        y_end[((size_t)c * B + (r0 + r)) * 512 + j] = S[cur][r][j];
}

// ---------------------------------------------------------------------------
// Combine: h(c) = y_end(c-1) + h(c-1) @ RL, block-floating-point scaled per
// (group g of NBC rows, c): stored h = true_h * 2^(-40E).
// h(c) is written IN PLACE over y_end(c-1) (read-before-write per thread);
// h(0) is never materialized (passB reads s0 directly for chunk 0).
// Grid: B/NBC workgroups, C-1 sequential steps each.
// ---------------------------------------------------------------------------
__global__ __launch_bounds__(512) void combine(float* __restrict__ yeh,
                                               const float* __restrict__ s0,
                                               const float* __restrict__ RL,
                                               int* __restrict__ Eout,
                                               int B, int C) {
    __shared__ float S[NBC][512];
    __shared__ float red[512];
    const int g  = blockIdx.x;
    const int G  = gridDim.x;       // B / NBC
    const int j  = threadIdx.x;
    const int r0 = g * NBC;

#pragma unroll
    for (int r = 0; r < NBC; ++r) {
        float v = s0[(size_t)(r0 + r) * 512 + j];
        S[r][j] = fminf(fmaxf(v, -LIM), LIM);
    }
    int E = 0;
    __syncthreads();

    const float* __restrict__ RLc = RL + j;

    for (int c = 1; c < C; ++c) {
        float acc[NBC] = {0.f, 0.f};
#pragma unroll 4
        for (int d = 0; d < 512; d += 4) {
            float rv0 = RLc[(size_t)(d + 0) * 512];
            float rv1 = RLc[(size_t)(d + 1) * 512];
            float rv2 = RLc[(size_t)(d + 2) * 512];
            float rv3 = RLc[(size_t)(d + 3) * 512];
#pragma unroll
            for (int r = 0; r < NBC; ++r) {
                float4 s4 = *(const float4*)&S[r][d];
                acc[r] = fmaf(s4.x, rv0, acc[r]);
                acc[r] = fmaf(s4.y, rv1, acc[r]);
                acc[r] = fmaf(s4.z, rv2, acc[r]);
                acc[r] = fmaf(s4.w, rv3, acc[r]);
            }
        }
        float us = ldexpf(1.f, -40 * E);  // underflow to 0 is fine
        float tmp[NBC];
        float mx = 0.f;
#pragma unroll
        for (int r = 0; r < NBC; ++r) {
            float ye = yeh[((size_t)(c - 1) * B + (r0 + r)) * 512 + j];
            float sn = fminf(fmaxf(fmaf(ye, us, acc[r]), -LIM), LIM);
            tmp[r] = sn;
            mx = fmaxf(mx, fabsf(sn));
        }
        __syncthreads();           // all reads of S done before overwrite
        red[j] = mx;
        __syncthreads();
#pragma unroll
        for (int w = 256; w > 0; w >>= 1) {
            if (j < w) red[j] = fmaxf(red[j], red[j + w]);
            __syncthreads();
        }
        float m = red[0];
        __syncthreads();
        if (m > RESCALE_THRESH) {
#pragma unroll
            for (int r = 0; r < NBC; ++r) tmp[r] *= SCL_DN;
            E += 1;
        }
#pragma unroll
        for (int r = 0; r < NBC; ++r) {
            S[r][j] = tmp[r];
            yeh[((size_t)(c - 1) * B + (r0 + r)) * 512 + j] = tmp[r];  // h(c) over ye(c-1)
        }
        if (j == 0) Eout[c * G + g] = E;
        __syncthreads();
    }
}

// ---------------------------------------------------------------------------
// Pass B: per (g, c), run the TRUE recurrence over the chunk starting from
// h(c) (scaled; per-NBC-row-pair exponents unified to the group max at load),
// write out_t = hopf(s_t) reconstructed in f64.
// NaN-proof: per-step NaN-dropping clamps; output clamped to +/-3e38.
// ---------------------------------------------------------------------------
__global__ __launch_bounds__(512) void passB(const float* __restrict__ R,
                                             const float* __restrict__ s0,
                                             const float* __restrict__ hbuf,
                                             const int* __restrict__ Ein,
                                             float* __restrict__ out,
                                             int T, int B, int Gc) {
    __shared__ float S[2][NB][512];
    __shared__ float red[512];
    const int g  = blockIdx.x;
    const int c  = blockIdx.y;
    const int j  = threadIdx.x;
    const int L  = T / CHUNKS;
    const int t0 = c * L;
    const int r0 = g * NB;

    int E = 0;
    if (c == 0) {
#pragma unroll
        for (int r = 0; r < NB; ++r) {
            float v = s0[(size_t)(r0 + r) * 512 + j];
            S[0][r][j] = fminf(fmaxf(v, -LIM), LIM);
        }
    } else {
        int Er[NB];
        int Em = 0;
#pragma unroll
        for (int r = 0; r < NB; ++r) {
            Er[r] = Ein[c * Gc + ((r0 + r) / NBC)];
            Em = (Er[r] > Em) ? Er[r] : Em;
        }
#pragma unroll
        for (int r = 0; r < NB; ++r) {
            float v = hbuf[((size_t)(c - 1) * B + (r0 + r)) * 512 + j];
            // unify exponents: stored' = stored * 2^(40*(Er-Em)), factor <= 1
            S[0][r][j] = (Er[r] == Em) ? v : v * ldexpf(1.f, 40 * (Er[r] - Em));
        }
        E = Em;
    }
    __syncthreads();

    double scaleE = ldexp(1.0, 40 * E);        // inf-safe (guarded below)
    float  uscale = ldexpf(1.f, -40 * E);      // underflow-to-0 is fine

    const float* __restrict__ Rc = R + j;
    int cur = 0;

    for (int t = t0; t < t0 + L; ++t) {
        float acc[NB] = {0.f,0.f,0.f,0.f,0.f,0.f,0.f,0.f};
        const float (* __restrict__ Sc)[512] = S[cur];
#pragma unroll 4
        for (int d = 0; d < 512; d += 4) {
            float rv0 = Rc[(size_t)(d + 0) * 512];
            float rv1 = Rc[(size_t)(d + 1) * 512];
            float rv2 = Rc[(size_t)(d + 2) * 512];
            float rv3 = Rc[(size_t)(d + 3) * 512];
#pragma unroll
            for (int r = 0; r < NB; ++r) {
                float4 s4 = *(const float4*)&Sc[r][d];
                acc[r] = fmaf(s4.x, rv0, acc[r]);
                acc[r] = fmaf(s4.y, rv1, acc[r]);
                acc[r] = fmaf(s4.z, rv2, acc[r]);
                acc[r] = fmaf(s4.w, rv3, acc[r]);
            }
        }
        float sn[NB];
        float mx = 0.f;
#pragma unroll
        for (int r = 0; r < NB; ++r) {
            size_t oi = ((size_t)(r0 + r) * T + t) * 512 + j;
            float u  = out[oi];
            float v  = fminf(fmaxf(fmaf(u, uscale, acc[r]), -LIM), LIM);
            sn[r] = v;
            mx = fmaxf(mx, fabsf(v));
            double sd = (double)v * scaleE;
            double ov = sd * (1.0 - sd * sd);
            double oc = fmin(fmax(ov, -3.0e38), 3.0e38);  // NaN -> finite
            oc = (oc == oc) ? oc : 0.0;
            out[oi] = (float)oc;
        }
        if ((t & 7) == 7) {      // uniform branch: periodic rescale
            red[j] = mx;
            __syncthreads();
#pragma unroll
            for (int w = 256; w > 0; w >>= 1) {
                if (j < w) red[j] = fmaxf(red[j], red[j + w]);
                __syncthreads();
            }
            float m = red[0];
            __syncthreads();
            if (m > RESCALE_THRESH) {
#pragma unroll
                for (int r = 0; r < NB; ++r) sn[r] *= SCL_DN;
                E += 1;
                scaleE *= 0x1p40;
                uscale *= SCL_DN;
            }
        }
#pragma unroll
        for (int r = 0; r < NB; ++r) S[cur ^ 1][r][j] = sn[r];
        __syncthreads();
        cur ^= 1;
    }
}

// ---------------------------------------------------------------------------
// Fallback (proven path): single-pass sequential recurrence.
// ---------------------------------------------------------------------------
__global__ __launch_bounds__(512) void recur(const float* __restrict__ R,
                                             const float* __restrict__ s0,
                                             float* __restrict__ out,
                                             int T) {
    __shared__ float sbuf[2][512];
    __shared__ float red[512];

    const int b = blockIdx.x;
    const int j = threadIdx.x;

    float sini = s0[(size_t)b * 512 + j];
    sbuf[0][j] = fminf(fmaxf(sini, -LIM), LIM);
    __syncthreads();

    const float* __restrict__ Rc = R + j;
    float* __restrict__ ob = out + (size_t)b * T * 512;

    int cur = 0;
    double scaleE = 1.0;
    float  uscale = 1.0f;

    for (int t = 0; t < T; ++t) {
        const float* s = sbuf[cur];
        float d0 = 0.f, d1 = 0.f, d2 = 0.f, d3 = 0.f;
#pragma unroll 8
        for (int d = 0; d < 512; d += 4) {
            d0 = fmaf(s[d + 0], Rc[(size_t)(d + 0) * 512], d0);
            d1 = fmaf(s[d + 1], Rc[(size_t)(d + 1) * 512], d1);
            d2 = fmaf(s[d + 2], Rc[(size_t)(d + 2) * 512], d2);
            d3 = fmaf(s[d + 3], Rc[(size_t)(d + 3) * 512], d3);
        }
        float u = ob[(size_t)t * 512 + j];
        float snew = fmaf(u, uscale, (d0 + d1) + (d2 + d3));
        snew = fminf(fmaxf(snew, -LIM), LIM);

        double sd = (double)snew * scaleE;
        double ov = sd * (1.0 - sd * sd);
        double oc = fmin(fmax(ov, -3.0e38), 3.0e38);
        oc = (oc == oc) ? oc : 0.0;
        ob[(size_t)t * 512 + j] = (float)oc;

        if ((t & 31) == 31) {
            red[j] = fabsf(snew);
            __syncthreads();
#pragma unroll
            for (int w = 256; w > 0; w >>= 1) {
                if (j < w) red[j] = fmaxf(red[j], red[j + w]);
                __syncthreads();
            }
            float m = red[0];
            __syncthreads();
            if (m > RESCALE_THRESH) {
                snew   *= SCL_DN;
                scaleE *= 0x1p40;
                uscale *= SCL_DN;
            }
        }

        sbuf[cur ^ 1][j] = snew;
        __syncthreads();
        cur ^= 1;
    }
}

// ---------------------------------------------------------------------------
extern "C" void kernel_launch(void* const* d_in, const int* in_sizes, int n_in,
                              void* d_out, int out_size, void* d_ws, size_t ws_size,
                              hipStream_t stream) {
    const float* x  = (const float*)d_in[0];  // [B, T, 512]
    const float* K  = (const float*)d_in[1];  // [512, 512]
    const float* R  = (const float*)d_in[2];  // [512, 512]
    const float* s0 = (const float*)d_in[3];  // [B, 512]
    float* out = (float*)d_out;               // [B, T, 512]

    const int D = 512;
    const int M = in_sizes[0] / D;   // B*T
    const int B = in_sizes[3] / D;   // 64
    const int T = M / B;             // 1024
    const int G  = B / NB;           // 8 batch groups (passA/passB)
    const int Gc = B / NBC;          // 32 combine groups

    // Phase 1: U = X@K into d_out (both paths need it).
    gemm_xk<<<dim3(D / BN, M / BM), 256, 0, stream>>>(x, K, out);

    // Workspace layout (bytes):
    //   [0, 1MB)   RLa (R^2, R^8)
    //   [1, 2MB)   RLb (R^4, R^16)
    //   [2, 10MB)  yeh: CHUNKS slots of B*D floats. Slot c (c<CHUNKS-1) holds
    //              y_end(c), later overwritten in place by h(c+1).
    //              Slot CHUNKS-1 is unused by floats -> hosts Ebuf (8 KB).
    const size_t MB = 1u << 20;
    const size_t slot = (size_t)B * D * sizeof(float);        // 128 KB
    const size_t off_RLa = 0;
    const size_t off_RLb = 1 * MB;
    const size_t off_yeh = 2 * MB;
    const size_t off_E   = off_yeh + (size_t)(CHUNKS - 1) * slot;
    const size_t need    = off_yeh + (size_t)CHUNKS * slot;   // 10 MB for B=64

    if (ws_size < need || (T % CHUNKS) != 0 || (B % NB) != 0 || (B % NBC) != 0 ||
        (size_t)CHUNKS * Gc * sizeof(int) > slot) {
        // Fallback: proven single-pass path.
        recur<<<B, D, 0, stream>>>(R, s0, out, T);
        return;
    }

    char* ws = (char*)d_ws;
    float* RLa  = (float*)(ws + off_RLa);
    float* RLb  = (float*)(ws + off_RLb);
    float* yeh  = (float*)(ws + off_yeh);
    int*   Ebuf = (int*)(ws + off_E);

    // Phase 2: RL = R^L by repeated squaring (L = T/CHUNKS = 16 = 2^4).
    dim3 sq(D / BN, D / BM);
    gemm_xk<<<sq, 256, 0, stream>>>(R,   R,   RLa);   // R^2
    gemm_xk<<<sq, 256, 0, stream>>>(RLa, RLa, RLb);   // R^4
    gemm_xk<<<sq, 256, 0, stream>>>(RLb, RLb, RLa);   // R^8
    gemm_xk<<<sq, 256, 0, stream>>>(RLa, RLa, RLb);   // R^16

    // Phase 3: local chunk endpoints (chunk CHUNKS-1's endpoint is unused).
    passA<<<dim3(G, CHUNKS - 1), 512, 0, stream>>>(out, R, yeh, T, B);

    // Phase 4: sequential combine across chunks (h in place + per-chunk exponent).
    combine<<<Gc, 512, 0, stream>>>(yeh, s0, RLb, Ebuf, B, CHUNKS);

    // Phase 5: true recurrence per chunk + hopf output.
    passB<<<dim3(G, CHUNKS), 512, 0, stream>>>(R, s0, yeh, Ebuf, out, T, B, Gc);
}

// Round 3
// 3176.495 us; speedup vs baseline: 1.0748x; 1.0037x over previous
//
#include <hip/hip_runtime.h>
#include <math.h>

#define NB      16     // batch rows per workgroup in passA/passB
#define NBC     2      // batch rows per workgroup in combine
#define CHUNKS  64     // time chunks (L = T/CHUNKS = 16)
#define LIM     0x1p100f
#define RESCALE_THRESH 0x1p44f
#define SCL_DN  0x1p-40f

// ---------------------------------------------------------------------------
// Generic tiled fp32 GEMM: C = A@B. A:[M,512], B:[512,512], C:[M,512].
// BM=BN=64, BK=16, 256 threads, 4x4 microtile, next-tile register prefetch.
// ---------------------------------------------------------------------------
#define BM 64
#define BN 64
#define BK 16

__global__ __launch_bounds__(256) void gemm_xk(const float* __restrict__ A,
                                               const float* __restrict__ B,
                                               float* __restrict__ C) {
    __shared__ float As[BK][BM + 4];
    __shared__ float Bs[BK][BN];

    const int tid  = threadIdx.x;
    const int col0 = blockIdx.x * BN;
    const int row0 = blockIdx.y * BM;

    const int tx = tid & 15;
    const int ty = tid >> 4;

    const int am = tid >> 2;
    const int ak = (tid & 3) << 2;
    const int bk  = tid >> 4;
    const int bn4 = (tid & 15) << 2;

    float acc[4][4] = {{0.f,0.f,0.f,0.f},{0.f,0.f,0.f,0.f},
                       {0.f,0.f,0.f,0.f},{0.f,0.f,0.f,0.f}};

    // prologue: load tile k0=0 into registers
    float4 av = *(const float4*)(A + (size_t)(row0 + am) * 512 + ak);
    float4 bv = *(const float4*)(B + (size_t)bk * 512 + (col0 + bn4));

    for (int k0 = 0; k0 < 512; k0 += BK) {
        __syncthreads();
        As[ak + 0][am] = av.x;
        As[ak + 1][am] = av.y;
        As[ak + 2][am] = av.z;
        As[ak + 3][am] = av.w;
        *(float4*)&Bs[bk][bn4] = bv;
        __syncthreads();
        if (k0 + BK < 512) {   // issue next-tile loads; they overlap the FMAs
            av = *(const float4*)(A + (size_t)(row0 + am) * 512 + (k0 + BK + ak));
            bv = *(const float4*)(B + (size_t)(k0 + BK + bk) * 512 + (col0 + bn4));
        }
#pragma unroll
        for (int k = 0; k < BK; ++k) {
            float4 a4 = *(const float4*)&As[k][ty << 2];
            float4 b4 = *(const float4*)&Bs[k][tx << 2];
            float ar[4] = {a4.x, a4.y, a4.z, a4.w};
            float br[4] = {b4.x, b4.y, b4.z, b4.w};
#pragma unroll
            for (int i = 0; i < 4; ++i)
#pragma unroll
                for (int j = 0; j < 4; ++j)
                    acc[i][j] = fmaf(ar[i], br[j], acc[i][j]);
        }
    }

#pragma unroll
    for (int i = 0; i < 4; ++i) {
        float4 v = make_float4(acc[i][0], acc[i][1], acc[i][2], acc[i][3]);
        *(float4*)(C + (size_t)(row0 + (ty << 2) + i) * 512 + col0 + (tx << 2)) = v;
    }
}

// ---------------------------------------------------------------------------
// Pass A: per (batch-group g of NB=16 rows, chunk c), local recurrence from
// ZERO state; store only y_end(c). Thread layout: cp = tid&255, rg = tid>>8.
// Thread owns rows rg*8..rg*8+7, columns {cp, cp+256}: each ds_read_b128 of
// state feeds 8 FMAs (2 cols x 4 k) -> half the LDS instructions per FLOP.
// Single-buffered state (two barriers per step).
// ---------------------------------------------------------------------------
__global__ __launch_bounds__(512) void passA(const float* __restrict__ U,
                                             const float* __restrict__ R,
                                             float* __restrict__ y_end,
                                             int T, int B) {
    __shared__ float S[NB][512];
    const int g   = blockIdx.x;
    const int c   = blockIdx.y;
    const int tid = threadIdx.x;
    const int cp  = tid & 255;
    const int rg  = tid >> 8;
    const int rb  = rg * 8;
    const int L   = T / CHUNKS;
    const int t0  = c * L;
    const int r0  = g * NB;
    const int j0  = cp;
    const int j1  = cp + 256;

#pragma unroll
    for (int r = 0; r < 8; ++r) { S[rb + r][j0] = 0.f; S[rb + r][j1] = 0.f; }
    __syncthreads();

    const float* __restrict__ R0 = R + j0;
    const float* __restrict__ R1 = R + j1;

    for (int t = t0; t < t0 + L; ++t) {
        // prefetch U for this step (latency hides under the matvec)
        float u0[8], u1[8];
#pragma unroll
        for (int r = 0; r < 8; ++r) {
            const float* Up = U + ((size_t)(r0 + rb + r) * T + t) * 512;
            u0[r] = Up[j0];
            u1[r] = Up[j1];
        }
        float a0[8] = {0.f,0.f,0.f,0.f,0.f,0.f,0.f,0.f};
        float a1[8] = {0.f,0.f,0.f,0.f,0.f,0.f,0.f,0.f};
#pragma unroll 4
        for (int d = 0; d < 512; d += 4) {
            float p00 = R0[(size_t)(d + 0) * 512];
            float p01 = R0[(size_t)(d + 1) * 512];
            float p02 = R0[(size_t)(d + 2) * 512];
            float p03 = R0[(size_t)(d + 3) * 512];
            float p10 = R1[(size_t)(d + 0) * 512];
            float p11 = R1[(size_t)(d + 1) * 512];
            float p12 = R1[(size_t)(d + 2) * 512];
            float p13 = R1[(size_t)(d + 3) * 512];
#pragma unroll
            for (int r = 0; r < 8; ++r) {
                float4 s4 = *(const float4*)&S[rb + r][d];
                a0[r] = fmaf(s4.x, p00, a0[r]);
                a0[r] = fmaf(s4.y, p01, a0[r]);
                a0[r] = fmaf(s4.z, p02, a0[r]);
                a0[r] = fmaf(s4.w, p03, a0[r]);
                a1[r] = fmaf(s4.x, p10, a1[r]);
                a1[r] = fmaf(s4.y, p11, a1[r]);
                a1[r] = fmaf(s4.z, p12, a1[r]);
                a1[r] = fmaf(s4.w, p13, a1[r]);
            }
        }
        __syncthreads();   // all reads of S complete
#pragma unroll
        for (int r = 0; r < 8; ++r) {
            S[rb + r][j0] = fminf(fmaxf(u0[r] + a0[r], -LIM), LIM);
            S[rb + r][j1] = fminf(fmaxf(u1[r] + a1[r], -LIM), LIM);
        }
        __syncthreads();
    }

#pragma unroll
    for (int r = 0; r < 8; ++r) {
        y_end[((size_t)c * B + (r0 + rb + r)) * 512 + j0] = S[rb + r][j0];
        y_end[((size_t)c * B + (r0 + rb + r)) * 512 + j1] = S[rb + r][j1];
    }
}

// ---------------------------------------------------------------------------
// Combine: h(c) = y_end(c-1) + h(c-1) @ RL, block-floating-point scaled per
// (group g of NBC rows, c). h(c) written IN PLACE over y_end(c-1).
// ---------------------------------------------------------------------------
__global__ __launch_bounds__(512) void combine(float* __restrict__ yeh,
                                               const float* __restrict__ s0,
                                               const float* __restrict__ RL,
                                               int* __restrict__ Eout,
                                               int B, int C) {
    __shared__ float S[NBC][512];
    __shared__ float red[512];
    const int g  = blockIdx.x;
    const int G  = gridDim.x;       // B / NBC
    const int j  = threadIdx.x;
    const int r0 = g * NBC;

#pragma unroll
    for (int r = 0; r < NBC; ++r) {
        float v = s0[(size_t)(r0 + r) * 512 + j];
        S[r][j] = fminf(fmaxf(v, -LIM), LIM);
    }
    int E = 0;
    __syncthreads();

    const float* __restrict__ RLc = RL + j;

    for (int c = 1; c < C; ++c) {
        float acc[NBC] = {0.f, 0.f};
#pragma unroll 4
        for (int d = 0; d < 512; d += 4) {
            float rv0 = RLc[(size_t)(d + 0) * 512];
            float rv1 = RLc[(size_t)(d + 1) * 512];
            float rv2 = RLc[(size_t)(d + 2) * 512];
            float rv3 = RLc[(size_t)(d + 3) * 512];
#pragma unroll
            for (int r = 0; r < NBC; ++r) {
                float4 s4 = *(const float4*)&S[r][d];
                acc[r] = fmaf(s4.x, rv0, acc[r]);
                acc[r] = fmaf(s4.y, rv1, acc[r]);
                acc[r] = fmaf(s4.z, rv2, acc[r]);
                acc[r] = fmaf(s4.w, rv3, acc[r]);
            }
        }
        float us = ldexpf(1.f, -40 * E);
        float tmp[NBC];
        float mx = 0.f;
#pragma unroll
        for (int r = 0; r < NBC; ++r) {
            float ye = yeh[((size_t)(c - 1) * B + (r0 + r)) * 512 + j];
            float sn = fminf(fmaxf(fmaf(ye, us, acc[r]), -LIM), LIM);
            tmp[r] = sn;
            mx = fmaxf(mx, fabsf(sn));
        }
        __syncthreads();
        red[j] = mx;
        __syncthreads();
#pragma unroll
        for (int w = 256; w > 0; w >>= 1) {
            if (j < w) red[j] = fmaxf(red[j], red[j + w]);
            __syncthreads();
        }
        float m = red[0];
        __syncthreads();
        if (m > RESCALE_THRESH) {
#pragma unroll
            for (int r = 0; r < NBC; ++r) tmp[r] *= SCL_DN;
            E += 1;
        }
#pragma unroll
        for (int r = 0; r < NBC; ++r) {
            S[r][j] = tmp[r];
            yeh[((size_t)(c - 1) * B + (r0 + r)) * 512 + j] = tmp[r];
        }
        if (j == 0) Eout[c * G + g] = E;
        __syncthreads();
    }
}

// ---------------------------------------------------------------------------
// Pass B: per (g of NB=16 rows, c), TRUE recurrence over the chunk starting
// from h(c) (exponents unified to wg max at load), out = hopf(s) in f64.
// Same 8-rows x 2-cols thread layout as passA; single-buffered state.
// ---------------------------------------------------------------------------
__global__ __launch_bounds__(512) void passB(const float* __restrict__ R,
                                             const float* __restrict__ s0,
                                             const float* __restrict__ hbuf,
                                             const int* __restrict__ Ein,
                                             float* __restrict__ out,
                                             int T, int B, int Gc) {
    __shared__ float S[NB][512];
    __shared__ float red[512];
    const int g   = blockIdx.x;
    const int c   = blockIdx.y;
    const int tid = threadIdx.x;
    const int cp  = tid & 255;
    const int rg  = tid >> 8;
    const int rb  = rg * 8;
    const int L   = T / CHUNKS;
    const int t0  = c * L;
    const int r0  = g * NB;
    const int j0  = cp;
    const int j1  = cp + 256;

    int E = 0;
    if (c == 0) {
#pragma unroll
        for (int r = 0; r < 8; ++r) {
            float v0 = s0[(size_t)(r0 + rb + r) * 512 + j0];
            float v1 = s0[(size_t)(r0 + rb + r) * 512 + j1];
            S[rb + r][j0] = fminf(fmaxf(v0, -LIM), LIM);
            S[rb + r][j1] = fminf(fmaxf(v1, -LIM), LIM);
        }
    } else {
        int Ep[NB / NBC];
        int Em = 0;
#pragma unroll
        for (int p = 0; p < NB / NBC; ++p) {
            Ep[p] = Ein[c * Gc + (r0 / NBC) + p];
            Em = (Ep[p] > Em) ? Ep[p] : Em;
        }
#pragma unroll
        for (int r = 0; r < 8; ++r) {
            int Er = Ep[(rb + r) >> 1];
            float f = (Er == Em) ? 1.f : ldexpf(1.f, 40 * (Er - Em));
            float v0 = hbuf[((size_t)(c - 1) * B + (r0 + rb + r)) * 512 + j0];
            float v1 = hbuf[((size_t)(c - 1) * B + (r0 + rb + r)) * 512 + j1];
            S[rb + r][j0] = v0 * f;
            S[rb + r][j1] = v1 * f;
        }
        E = Em;
    }
    __syncthreads();

    double scaleE = ldexp(1.0, 40 * E);
    float  uscale = ldexpf(1.f, -40 * E);

    const float* __restrict__ R0 = R + j0;
    const float* __restrict__ R1 = R + j1;

    for (int t = t0; t < t0 + L; ++t) {
        // prefetch U (current out values) for this step
        float u0[8], u1[8];
        size_t oi0[8];
#pragma unroll
        for (int r = 0; r < 8; ++r) {
            size_t base = ((size_t)(r0 + rb + r) * T + t) * 512;
            oi0[r] = base;
            u0[r] = out[base + j0];
            u1[r] = out[base + j1];
        }
        float a0[8] = {0.f,0.f,0.f,0.f,0.f,0.f,0.f,0.f};
        float a1[8] = {0.f,0.f,0.f,0.f,0.f,0.f,0.f,0.f};
#pragma unroll 4
        for (int d = 0; d < 512; d += 4) {
            float p00 = R0[(size_t)(d + 0) * 512];
            float p01 = R0[(size_t)(d + 1) * 512];
            float p02 = R0[(size_t)(d + 2) * 512];
            float p03 = R0[(size_t)(d + 3) * 512];
            float p10 = R1[(size_t)(d + 0) * 512];
            float p11 = R1[(size_t)(d + 1) * 512];
            float p12 = R1[(size_t)(d + 2) * 512];
            float p13 = R1[(size_t)(d + 3) * 512];
#pragma unroll
            for (int r = 0; r < 8; ++r) {
                float4 s4 = *(const float4*)&S[rb + r][d];
                a0[r] = fmaf(s4.x, p00, a0[r]);
                a0[r] = fmaf(s4.y, p01, a0[r]);
                a0[r] = fmaf(s4.z, p02, a0[r]);
                a0[r] = fmaf(s4.w, p03, a0[r]);
                a1[r] = fmaf(s4.x, p10, a1[r]);
                a1[r] = fmaf(s4.y, p11, a1[r]);
                a1[r] = fmaf(s4.z, p12, a1[r]);
                a1[r] = fmaf(s4.w, p13, a1[r]);
            }
        }
        float s0n[8], s1n[8];
        float mx = 0.f;
#pragma unroll
        for (int r = 0; r < 8; ++r) {
            float v0 = fminf(fmaxf(fmaf(u0[r], uscale, a0[r]), -LIM), LIM);
            float v1 = fminf(fmaxf(fmaf(u1[r], uscale, a1[r]), -LIM), LIM);
            s0n[r] = v0; s1n[r] = v1;
            mx = fmaxf(mx, fmaxf(fabsf(v0), fabsf(v1)));
            double sd0 = (double)v0 * scaleE;
            double ov0 = sd0 * (1.0 - sd0 * sd0);
            double oc0 = fmin(fmax(ov0, -3.0e38), 3.0e38);
            oc0 = (oc0 == oc0) ? oc0 : 0.0;
            out[oi0[r] + j0] = (float)oc0;
            double sd1 = (double)v1 * scaleE;
            double ov1 = sd1 * (1.0 - sd1 * sd1);
            double oc1 = fmin(fmax(ov1, -3.0e38), 3.0e38);
            oc1 = (oc1 == oc1) ? oc1 : 0.0;
            out[oi0[r] + j1] = (float)oc1;
        }
        if ((t & 7) == 7) {      // periodic rescale (barriers close read phase)
            red[tid] = mx;
            __syncthreads();
#pragma unroll
            for (int w = 256; w > 0; w >>= 1) {
                if (tid < w) red[tid] = fmaxf(red[tid], red[tid + w]);
                __syncthreads();
            }
            float m = red[0];
            __syncthreads();
            if (m > RESCALE_THRESH) {
#pragma unroll
                for (int r = 0; r < 8; ++r) { s0n[r] *= SCL_DN; s1n[r] *= SCL_DN; }
                E += 1;
                scaleE *= 0x1p40;
                uscale *= SCL_DN;
            }
        } else {
            __syncthreads();     // close read phase before overwriting S
        }
#pragma unroll
        for (int r = 0; r < 8; ++r) {
            S[rb + r][j0] = s0n[r];
            S[rb + r][j1] = s1n[r];
        }
        __syncthreads();
    }
}

// ---------------------------------------------------------------------------
// Fallback (proven path): single-pass sequential recurrence.
// ---------------------------------------------------------------------------
__global__ __launch_bounds__(512) void recur(const float* __restrict__ R,
                                             const float* __restrict__ s0,
                                             float* __restrict__ out,
                                             int T) {
    __shared__ float sbuf[2][512];
    __shared__ float red[512];

    const int b = blockIdx.x;
    const int j = threadIdx.x;

    float sini = s0[(size_t)b * 512 + j];
    sbuf[0][j] = fminf(fmaxf(sini, -LIM), LIM);
    __syncthreads();

    const float* __restrict__ Rc = R + j;
    float* __restrict__ ob = out + (size_t)b * T * 512;

    int cur = 0;
    double scaleE = 1.0;
    float  uscale = 1.0f;

    for (int t = 0; t < T; ++t) {
        const float* s = sbuf[cur];
        float d0 = 0.f, d1 = 0.f, d2 = 0.f, d3 = 0.f;
#pragma unroll 8
        for (int d = 0; d < 512; d += 4) {
            d0 = fmaf(s[d + 0], Rc[(size_t)(d + 0) * 512], d0);
            d1 = fmaf(s[d + 1], Rc[(size_t)(d + 1) * 512], d1);
            d2 = fmaf(s[d + 2], Rc[(size_t)(d + 2) * 512], d2);
            d3 = fmaf(s[d + 3], Rc[(size_t)(d + 3) * 512], d3);
        }
        float u = ob[(size_t)t * 512 + j];
        float snew = fmaf(u, uscale, (d0 + d1) + (d2 + d3));
        snew = fminf(fmaxf(snew, -LIM), LIM);

        double sd = (double)snew * scaleE;
        double ov = sd * (1.0 - sd * sd);
        double oc = fmin(fmax(ov, -3.0e38), 3.0e38);
        oc = (oc == oc) ? oc : 0.0;
        ob[(size_t)t * 512 + j] = (float)oc;

        if ((t & 31) == 31) {
            red[j] = fabsf(snew);
            __syncthreads();
#pragma unroll
            for (int w = 256; w > 0; w >>= 1) {
                if (j < w) red[j] = fmaxf(red[j], red[j + w]);
                __syncthreads();
            }
            float m = red[0];
            __syncthreads();
            if (m > RESCALE_THRESH) {
                snew   *= SCL_DN;
                scaleE *= 0x1p40;
                uscale *= SCL_DN;
            }
        }

        sbuf[cur ^ 1][j] = snew;
        __syncthreads();
        cur ^= 1;
    }
}

// ---------------------------------------------------------------------------
extern "C" void kernel_launch(void* const* d_in, const int* in_sizes, int n_in,
                              void* d_out, int out_size, void* d_ws, size_t ws_size,
                              hipStream_t stream) {
    const float* x  = (const float*)d_in[0];  // [B, T, 512]
    const float* K  = (const float*)d_in[1];  // [512, 512]
    const float* R  = (const float*)d_in[2];  // [512, 512]
    const float* s0 = (const float*)d_in[3];  // [B, 512]
    float* out = (float*)d_out;               // [B, T, 512]

    const int D = 512;
    const int M = in_sizes[0] / D;   // B*T
    const int B = in_sizes[3] / D;   // 64
    const int T = M / B;             // 1024
    const int G  = B / NB;           // 4 batch groups (passA/passB)
    const int Gc = B / NBC;          // 32 combine groups

    // Phase 1: U = X@K into d_out (both paths need it).
    gemm_xk<<<dim3(D / BN, M / BM), 256, 0, stream>>>(x, K, out);

    // Workspace layout (bytes):
    //   [0, 1MB)   RLa (R^2, R^8)
    //   [1, 2MB)   RLb (R^4, R^16)
    //   [2, 10MB)  yeh: CHUNKS slots of B*D floats. Slot c (c<CHUNKS-1) holds
    //              y_end(c), later overwritten in place by h(c+1).
    //              Slot CHUNKS-1 hosts Ebuf (8 KB).
    const size_t MB = 1u << 20;
    const size_t slot = (size_t)B * D * sizeof(float);        // 128 KB
    const size_t off_RLa = 0;
    const size_t off_RLb = 1 * MB;
    const size_t off_yeh = 2 * MB;
    const size_t off_E   = off_yeh + (size_t)(CHUNKS - 1) * slot;
    const size_t need    = off_yeh + (size_t)CHUNKS * slot;   // 10 MB for B=64

    if (ws_size < need || (T % CHUNKS) != 0 || (B % NB) != 0 || (B % NBC) != 0 ||
        D != 512 || (size_t)CHUNKS * Gc * sizeof(int) > slot) {
        // Fallback: proven single-pass path.
        recur<<<B, D, 0, stream>>>(R, s0, out, T);
        return;
    }

    char* ws = (char*)d_ws;
    float* RLa  = (float*)(ws + off_RLa);
    float* RLb  = (float*)(ws + off_RLb);
    float* yeh  = (float*)(ws + off_yeh);
    int*   Ebuf = (int*)(ws + off_E);

    // Phase 2: RL = R^L by repeated squaring (L = T/CHUNKS = 16 = 2^4).
    dim3 sq(D / BN, D / BM);
    gemm_xk<<<sq, 256, 0, stream>>>(R,   R,   RLa);   // R^2
    gemm_xk<<<sq, 256, 0, stream>>>(RLa, RLa, RLb);   // R^4
    gemm_xk<<<sq, 256, 0, stream>>>(RLb, RLb, RLa);   // R^8
    gemm_xk<<<sq, 256, 0, stream>>>(RLa, RLa, RLb);   // R^16

    // Phase 3: local chunk endpoints (chunk CHUNKS-1's endpoint is unused).
    passA<<<dim3(G, CHUNKS - 1), 512, 0, stream>>>(out, R, yeh, T, B);

    // Phase 4: sequential combine across chunks (h in place + per-chunk exponent).
    combine<<<Gc, 512, 0, stream>>>(yeh, s0, RLb, Ebuf, B, CHUNKS);

    // Phase 5: true recurrence per chunk + hopf output.
    passB<<<dim3(G, CHUNKS), 512, 0, stream>>>(R, s0, yeh, Ebuf, out, T, B, Gc);
}

// Round 4
// 3000.813 us; speedup vs baseline: 1.1378x; 1.0585x over previous
//
#include <hip/hip_runtime.h>
#include <math.h>

#define NB      8      // batch rows per workgroup in passA/passB
#define NBC     2      // batch rows per workgroup in combine
#define CHUNKS  64     // time chunks (L = T/CHUNKS = 16)
#define LIM     0x1p100f
#define RESCALE_THRESH 0x1p44f
#define SCL_DN  0x1p-40f

// ---------------------------------------------------------------------------
// Generic tiled fp32 GEMM: C = A@B. A:[M,512], B:[512,512], C:[M,512].
// BM=BN=64, BK=16, 256 threads, 4x4 microtile, next-tile register prefetch.
// ---------------------------------------------------------------------------
#define BM 64
#define BN 64
#define BK 16

__global__ __launch_bounds__(256) void gemm_xk(const float* __restrict__ A,
                                               const float* __restrict__ B,
                                               float* __restrict__ C) {
    __shared__ float As[BK][BM + 4];
    __shared__ float Bs[BK][BN];

    const int tid  = threadIdx.x;
    const int col0 = blockIdx.x * BN;
    const int row0 = blockIdx.y * BM;

    const int tx = tid & 15;
    const int ty = tid >> 4;

    const int am = tid >> 2;
    const int ak = (tid & 3) << 2;
    const int bk  = tid >> 4;
    const int bn4 = (tid & 15) << 2;

    float acc[4][4] = {{0.f,0.f,0.f,0.f},{0.f,0.f,0.f,0.f},
                       {0.f,0.f,0.f,0.f},{0.f,0.f,0.f,0.f}};

    // prologue: load tile k0=0 into registers
    float4 av = *(const float4*)(A + (size_t)(row0 + am) * 512 + ak);
    float4 bv = *(const float4*)(B + (size_t)bk * 512 + (col0 + bn4));

    for (int k0 = 0; k0 < 512; k0 += BK) {
        __syncthreads();
        As[ak + 0][am] = av.x;
        As[ak + 1][am] = av.y;
        As[ak + 2][am] = av.z;
        As[ak + 3][am] = av.w;
        *(float4*)&Bs[bk][bn4] = bv;
        __syncthreads();
        if (k0 + BK < 512) {   // issue next-tile loads; they overlap the FMAs
            av = *(const float4*)(A + (size_t)(row0 + am) * 512 + (k0 + BK + ak));
            bv = *(const float4*)(B + (size_t)(k0 + BK + bk) * 512 + (col0 + bn4));
        }
#pragma unroll
        for (int k = 0; k < BK; ++k) {
            float4 a4 = *(const float4*)&As[k][ty << 2];
            float4 b4 = *(const float4*)&Bs[k][tx << 2];
            float ar[4] = {a4.x, a4.y, a4.z, a4.w};
            float br[4] = {b4.x, b4.y, b4.z, b4.w};
#pragma unroll
            for (int i = 0; i < 4; ++i)
#pragma unroll
                for (int j = 0; j < 4; ++j)
                    acc[i][j] = fmaf(ar[i], br[j], acc[i][j]);
        }
    }

#pragma unroll
    for (int i = 0; i < 4; ++i) {
        float4 v = make_float4(acc[i][0], acc[i][1], acc[i][2], acc[i][3]);
        *(float4*)(C + (size_t)(row0 + (ty << 2) + i) * 512 + col0 + (tx << 2)) = v;
    }
}

// ---------------------------------------------------------------------------
// Pass A: per (batch-group g of NB=8 rows, chunk c), local recurrence from
// ZERO state; store only y_end(c). W=256 threads: thread owns all 8 rows,
// columns {tid, tid+256}. Each ds_read_b128 feeds 8 FMAs. Grid = 512 wgs
// -> 2 independent wgs/CU (decoupled barrier domains fill each other's
// stalls). Single-buffered state, two barriers per step.
// ---------------------------------------------------------------------------
__global__ __launch_bounds__(256) void passA(const float* __restrict__ U,
                                             const float* __restrict__ R,
                                             float* __restrict__ y_end,
                                             int T, int B) {
    __shared__ float S[NB][512];
    const int g   = blockIdx.x;
    const int c   = blockIdx.y;
    const int tid = threadIdx.x;
    const int L   = T / CHUNKS;
    const int t0  = c * L;
    const int r0  = g * NB;
    const int j0  = tid;
    const int j1  = tid + 256;

#pragma unroll
    for (int r = 0; r < NB; ++r) { S[r][j0] = 0.f; S[r][j1] = 0.f; }
    __syncthreads();

    const float* __restrict__ R0 = R + j0;
    const float* __restrict__ R1 = R + j1;

    for (int t = t0; t < t0 + L; ++t) {
        // prefetch U for this step (latency hides under the matvec)
        float u0[NB], u1[NB];
#pragma unroll
        for (int r = 0; r < NB; ++r) {
            const float* Up = U + ((size_t)(r0 + r) * T + t) * 512;
            u0[r] = Up[j0];
            u1[r] = Up[j1];
        }
        float a0[NB] = {0.f,0.f,0.f,0.f,0.f,0.f,0.f,0.f};
        float a1[NB] = {0.f,0.f,0.f,0.f,0.f,0.f,0.f,0.f};
#pragma unroll 4
        for (int d = 0; d < 512; d += 4) {
            float p00 = R0[(size_t)(d + 0) * 512];
            float p01 = R0[(size_t)(d + 1) * 512];
            float p02 = R0[(size_t)(d + 2) * 512];
            float p03 = R0[(size_t)(d + 3) * 512];
            float p10 = R1[(size_t)(d + 0) * 512];
            float p11 = R1[(size_t)(d + 1) * 512];
            float p12 = R1[(size_t)(d + 2) * 512];
            float p13 = R1[(size_t)(d + 3) * 512];
#pragma unroll
            for (int r = 0; r < NB; ++r) {
                float4 s4 = *(const float4*)&S[r][d];
                a0[r] = fmaf(s4.x, p00, a0[r]);
                a0[r] = fmaf(s4.y, p01, a0[r]);
                a0[r] = fmaf(s4.z, p02, a0[r]);
                a0[r] = fmaf(s4.w, p03, a0[r]);
                a1[r] = fmaf(s4.x, p10, a1[r]);
                a1[r] = fmaf(s4.y, p11, a1[r]);
                a1[r] = fmaf(s4.z, p12, a1[r]);
                a1[r] = fmaf(s4.w, p13, a1[r]);
            }
        }
        __syncthreads();   // all reads of S complete
#pragma unroll
        for (int r = 0; r < NB; ++r) {
            S[r][j0] = fminf(fmaxf(u0[r] + a0[r], -LIM), LIM);
            S[r][j1] = fminf(fmaxf(u1[r] + a1[r], -LIM), LIM);
        }
        __syncthreads();
    }

#pragma unroll
    for (int r = 0; r < NB; ++r) {
        y_end[((size_t)c * B + (r0 + r)) * 512 + j0] = S[r][j0];
        y_end[((size_t)c * B + (r0 + r)) * 512 + j1] = S[r][j1];
    }
}

// ---------------------------------------------------------------------------
// Combine: h(c) = y_end(c-1) + h(c-1) @ RL, block-floating-point scaled per
// (group g of NBC rows, c). h(c) written IN PLACE over y_end(c-1).
// Rescale-max via wave shuffle reduce (2 barriers/step instead of ~20).
// ---------------------------------------------------------------------------
__global__ __launch_bounds__(512) void combine(float* __restrict__ yeh,
                                               const float* __restrict__ s0,
                                               const float* __restrict__ RL,
                                               int* __restrict__ Eout,
                                               int B, int C) {
    __shared__ float S[NBC][512];
    __shared__ float red[8];
    const int g  = blockIdx.x;
    const int G  = gridDim.x;       // B / NBC
    const int j  = threadIdx.x;
    const int r0 = g * NBC;

#pragma unroll
    for (int r = 0; r < NBC; ++r) {
        float v = s0[(size_t)(r0 + r) * 512 + j];
        S[r][j] = fminf(fmaxf(v, -LIM), LIM);
    }
    int E = 0;
    __syncthreads();

    const float* __restrict__ RLc = RL + j;

    for (int c = 1; c < C; ++c) {
        float acc[NBC] = {0.f, 0.f};
#pragma unroll 4
        for (int d = 0; d < 512; d += 4) {
            float rv0 = RLc[(size_t)(d + 0) * 512];
            float rv1 = RLc[(size_t)(d + 1) * 512];
            float rv2 = RLc[(size_t)(d + 2) * 512];
            float rv3 = RLc[(size_t)(d + 3) * 512];
#pragma unroll
            for (int r = 0; r < NBC; ++r) {
                float4 s4 = *(const float4*)&S[r][d];
                acc[r] = fmaf(s4.x, rv0, acc[r]);
                acc[r] = fmaf(s4.y, rv1, acc[r]);
                acc[r] = fmaf(s4.z, rv2, acc[r]);
                acc[r] = fmaf(s4.w, rv3, acc[r]);
            }
        }
        float us = ldexpf(1.f, -40 * E);
        float tmp[NBC];
        float mx = 0.f;
#pragma unroll
        for (int r = 0; r < NBC; ++r) {
            float ye = yeh[((size_t)(c - 1) * B + (r0 + r)) * 512 + j];
            float sn = fminf(fmaxf(fmaf(ye, us, acc[r]), -LIM), LIM);
            tmp[r] = sn;
            mx = fmaxf(mx, fabsf(sn));
        }
        // wave-level max reduce, then cross-wave via 8-slot LDS
        float m = mx;
#pragma unroll
        for (int o = 32; o > 0; o >>= 1) m = fmaxf(m, __shfl_xor(m, o));
        if ((j & 63) == 0) red[j >> 6] = m;
        __syncthreads();   // closes S-read phase AND publishes red[]
        m = fmaxf(fmaxf(fmaxf(red[0], red[1]), fmaxf(red[2], red[3])),
                  fmaxf(fmaxf(red[4], red[5]), fmaxf(red[6], red[7])));
        if (m > RESCALE_THRESH) {
#pragma unroll
            for (int r = 0; r < NBC; ++r) tmp[r] *= SCL_DN;
            E += 1;
        }
#pragma unroll
        for (int r = 0; r < NBC; ++r) {
            S[r][j] = tmp[r];
            yeh[((size_t)(c - 1) * B + (r0 + r)) * 512 + j] = tmp[r];
        }
        if (j == 0) Eout[c * G + g] = E;
        __syncthreads();
    }
}

// ---------------------------------------------------------------------------
// Pass B: per (g of NB=8 rows, c), TRUE recurrence over the chunk starting
// from h(c) (exponents unified to wg max at load), out = hopf(s) in f64.
// W=256 threads, 8 rows x 2 cols per thread; 2 wgs/CU; shuffle-based
// rescale reduce.
// ---------------------------------------------------------------------------
__global__ __launch_bounds__(256) void passB(const float* __restrict__ R,
                                             const float* __restrict__ s0,
                                             const float* __restrict__ hbuf,
                                             const int* __restrict__ Ein,
                                             float* __restrict__ out,
                                             int T, int B, int Gc) {
    __shared__ float S[NB][512];
    __shared__ float red[4];
    const int g   = blockIdx.x;
    const int c   = blockIdx.y;
    const int tid = threadIdx.x;
    const int L   = T / CHUNKS;
    const int t0  = c * L;
    const int r0  = g * NB;
    const int j0  = tid;
    const int j1  = tid + 256;

    int E = 0;
    if (c == 0) {
#pragma unroll
        for (int r = 0; r < NB; ++r) {
            float v0 = s0[(size_t)(r0 + r) * 512 + j0];
            float v1 = s0[(size_t)(r0 + r) * 512 + j1];
            S[r][j0] = fminf(fmaxf(v0, -LIM), LIM);
            S[r][j1] = fminf(fmaxf(v1, -LIM), LIM);
        }
    } else {
        int Ep[NB / NBC];
        int Em = 0;
#pragma unroll
        for (int p = 0; p < NB / NBC; ++p) {
            Ep[p] = Ein[c * Gc + (r0 / NBC) + p];
            Em = (Ep[p] > Em) ? Ep[p] : Em;
        }
#pragma unroll
        for (int r = 0; r < NB; ++r) {
            int Er = Ep[r >> 1];
            float f = (Er == Em) ? 1.f : ldexpf(1.f, 40 * (Er - Em));
            float v0 = hbuf[((size_t)(c - 1) * B + (r0 + r)) * 512 + j0];
            float v1 = hbuf[((size_t)(c - 1) * B + (r0 + r)) * 512 + j1];
            S[r][j0] = v0 * f;
            S[r][j1] = v1 * f;
        }
        E = Em;
    }
    __syncthreads();

    double scaleE = ldexp(1.0, 40 * E);
    float  uscale = ldexpf(1.f, -40 * E);

    const float* __restrict__ R0 = R + j0;
    const float* __restrict__ R1 = R + j1;

    for (int t = t0; t < t0 + L; ++t) {
        // prefetch U (current out values) for this step
        float u0[NB], u1[NB];
        size_t oi0[NB];
#pragma unroll
        for (int r = 0; r < NB; ++r) {
            size_t base = ((size_t)(r0 + r) * T + t) * 512;
            oi0[r] = base;
            u0[r] = out[base + j0];
            u1[r] = out[base + j1];
        }
        float a0[NB] = {0.f,0.f,0.f,0.f,0.f,0.f,0.f,0.f};
        float a1[NB] = {0.f,0.f,0.f,0.f,0.f,0.f,0.f,0.f};
#pragma unroll 4
        for (int d = 0; d < 512; d += 4) {
            float p00 = R0[(size_t)(d + 0) * 512];
            float p01 = R0[(size_t)(d + 1) * 512];
            float p02 = R0[(size_t)(d + 2) * 512];
            float p03 = R0[(size_t)(d + 3) * 512];
            float p10 = R1[(size_t)(d + 0) * 512];
            float p11 = R1[(size_t)(d + 1) * 512];
            float p12 = R1[(size_t)(d + 2) * 512];
            float p13 = R1[(size_t)(d + 3) * 512];
#pragma unroll
            for (int r = 0; r < NB; ++r) {
                float4 s4 = *(const float4*)&S[r][d];
                a0[r] = fmaf(s4.x, p00, a0[r]);
                a0[r] = fmaf(s4.y, p01, a0[r]);
                a0[r] = fmaf(s4.z, p02, a0[r]);
                a0[r] = fmaf(s4.w, p03, a0[r]);
                a1[r] = fmaf(s4.x, p10, a1[r]);
                a1[r] = fmaf(s4.y, p11, a1[r]);
                a1[r] = fmaf(s4.z, p12, a1[r]);
                a1[r] = fmaf(s4.w, p13, a1[r]);
            }
        }
        float s0n[NB], s1n[NB];
        float mx = 0.f;
#pragma unroll
        for (int r = 0; r < NB; ++r) {
            float v0 = fminf(fmaxf(fmaf(u0[r], uscale, a0[r]), -LIM), LIM);
            float v1 = fminf(fmaxf(fmaf(u1[r], uscale, a1[r]), -LIM), LIM);
            s0n[r] = v0; s1n[r] = v1;
            mx = fmaxf(mx, fmaxf(fabsf(v0), fabsf(v1)));
            double sd0 = (double)v0 * scaleE;
            double ov0 = sd0 * (1.0 - sd0 * sd0);
            double oc0 = fmin(fmax(ov0, -3.0e38), 3.0e38);
            oc0 = (oc0 == oc0) ? oc0 : 0.0;
            out[oi0[r] + j0] = (float)oc0;
            double sd1 = (double)v1 * scaleE;
            double ov1 = sd1 * (1.0 - sd1 * sd1);
            double oc1 = fmin(fmax(ov1, -3.0e38), 3.0e38);
            oc1 = (oc1 == oc1) ? oc1 : 0.0;
            out[oi0[r] + j1] = (float)oc1;
        }
        if ((t & 7) == 7) {      // periodic rescale (uniform branch)
            float m = mx;
#pragma unroll
            for (int o = 32; o > 0; o >>= 1) m = fmaxf(m, __shfl_xor(m, o));
            if ((tid & 63) == 0) red[tid >> 6] = m;
            __syncthreads();     // closes S-read phase AND publishes red[]
            m = fmaxf(fmaxf(red[0], red[1]), fmaxf(red[2], red[3]));
            if (m > RESCALE_THRESH) {
#pragma unroll
                for (int r = 0; r < NB; ++r) { s0n[r] *= SCL_DN; s1n[r] *= SCL_DN; }
                E += 1;
                scaleE *= 0x1p40;
                uscale *= SCL_DN;
            }
        } else {
            __syncthreads();     // close read phase before overwriting S
        }
#pragma unroll
        for (int r = 0; r < NB; ++r) {
            S[r][j0] = s0n[r];
            S[r][j1] = s1n[r];
        }
        __syncthreads();
    }
}

// ---------------------------------------------------------------------------
// Fallback (proven path): single-pass sequential recurrence.
// ---------------------------------------------------------------------------
__global__ __launch_bounds__(512) void recur(const float* __restrict__ R,
                                             const float* __restrict__ s0,
                                             float* __restrict__ out,
                                             int T) {
    __shared__ float sbuf[2][512];
    __shared__ float red[512];

    const int b = blockIdx.x;
    const int j = threadIdx.x;

    float sini = s0[(size_t)b * 512 + j];
    sbuf[0][j] = fminf(fmaxf(sini, -LIM), LIM);
    __syncthreads();

    const float* __restrict__ Rc = R + j;
    float* __restrict__ ob = out + (size_t)b * T * 512;

    int cur = 0;
    double scaleE = 1.0;
    float  uscale = 1.0f;

    for (int t = 0; t < T; ++t) {
        const float* s = sbuf[cur];
        float d0 = 0.f, d1 = 0.f, d2 = 0.f, d3 = 0.f;
#pragma unroll 8
        for (int d = 0; d < 512; d += 4) {
            d0 = fmaf(s[d + 0], Rc[(size_t)(d + 0) * 512], d0);
            d1 = fmaf(s[d + 1], Rc[(size_t)(d + 1) * 512], d1);
            d2 = fmaf(s[d + 2], Rc[(size_t)(d + 2) * 512], d2);
            d3 = fmaf(s[d + 3], Rc[(size_t)(d + 3) * 512], d3);
        }
        float u = ob[(size_t)t * 512 + j];
        float snew = fmaf(u, uscale, (d0 + d1) + (d2 + d3));
        snew = fminf(fmaxf(snew, -LIM), LIM);

        double sd = (double)snew * scaleE;
        double ov = sd * (1.0 - sd * sd);
        double oc = fmin(fmax(ov, -3.0e38), 3.0e38);
        oc = (oc == oc) ? oc : 0.0;
        ob[(size_t)t * 512 + j] = (float)oc;

        if ((t & 31) == 31) {
            red[j] = fabsf(snew);
            __syncthreads();
#pragma unroll
            for (int w = 256; w > 0; w >>= 1) {
                if (j < w) red[j] = fmaxf(red[j], red[j + w]);
                __syncthreads();
            }
            float m = red[0];
            __syncthreads();
            if (m > RESCALE_THRESH) {
                snew   *= SCL_DN;
                scaleE *= 0x1p40;
                uscale *= SCL_DN;
            }
        }

        sbuf[cur ^ 1][j] = snew;
        __syncthreads();
        cur ^= 1;
    }
}

// ---------------------------------------------------------------------------
extern "C" void kernel_launch(void* const* d_in, const int* in_sizes, int n_in,
                              void* d_out, int out_size, void* d_ws, size_t ws_size,
                              hipStream_t stream) {
    const float* x  = (const float*)d_in[0];  // [B, T, 512]
    const float* K  = (const float*)d_in[1];  // [512, 512]
    const float* R  = (const float*)d_in[2];  // [512, 512]
    const float* s0 = (const float*)d_in[3];  // [B, 512]
    float* out = (float*)d_out;               // [B, T, 512]

    const int D = 512;
    const int M = in_sizes[0] / D;   // B*T
    const int B = in_sizes[3] / D;   // 64
    const int T = M / B;             // 1024
    const int G  = B / NB;           // 8 batch groups (passA/passB)
    const int Gc = B / NBC;          // 32 combine groups

    // Phase 1: U = X@K into d_out (both paths need it).
    gemm_xk<<<dim3(D / BN, M / BM), 256, 0, stream>>>(x, K, out);

    // Workspace layout (bytes):
    //   [0, 1MB)   RLa (R^2, R^8)
    //   [1, 2MB)   RLb (R^4, R^16)
    //   [2, 10MB)  yeh: CHUNKS slots of B*D floats. Slot c (c<CHUNKS-1) holds
    //              y_end(c), later overwritten in place by h(c+1).
    //              Slot CHUNKS-1 hosts Ebuf (8 KB).
    const size_t MB = 1u << 20;
    const size_t slot = (size_t)B * D * sizeof(float);        // 128 KB
    const size_t off_RLa = 0;
    const size_t off_RLb = 1 * MB;
    const size_t off_yeh = 2 * MB;
    const size_t off_E   = off_yeh + (size_t)(CHUNKS - 1) * slot;
    const size_t need    = off_yeh + (size_t)CHUNKS * slot;   // 10 MB for B=64

    if (ws_size < need || (T % CHUNKS) != 0 || (B % NB) != 0 || (B % NBC) != 0 ||
        D != 512 || (size_t)CHUNKS * Gc * sizeof(int) > slot) {
        // Fallback: proven single-pass path.
        recur<<<B, D, 0, stream>>>(R, s0, out, T);
        return;
    }

    char* ws = (char*)d_ws;
    float* RLa  = (float*)(ws + off_RLa);
    float* RLb  = (float*)(ws + off_RLb);
    float* yeh  = (float*)(ws + off_yeh);
    int*   Ebuf = (int*)(ws + off_E);

    // Phase 2: RL = R^L by repeated squaring (L = T/CHUNKS = 16 = 2^4).
    dim3 sq(D / BN, D / BM);
    gemm_xk<<<sq, 256, 0, stream>>>(R,   R,   RLa);   // R^2
    gemm_xk<<<sq, 256, 0, stream>>>(RLa, RLa, RLb);   // R^4
    gemm_xk<<<sq, 256, 0, stream>>>(RLb, RLb, RLa);   // R^8
    gemm_xk<<<sq, 256, 0, stream>>>(RLa, RLa, RLb);   // R^16

    // Phase 3: local chunk endpoints (chunk CHUNKS-1's endpoint is unused).
    passA<<<dim3(G, CHUNKS - 1), 256, 0, stream>>>(out, R, yeh, T, B);

    // Phase 4: sequential combine across chunks (h in place + per-chunk exponent).
    combine<<<Gc, 512, 0, stream>>>(yeh, s0, RLb, Ebuf, B, CHUNKS);

    // Phase 5: true recurrence per chunk + hopf output.
    passB<<<dim3(G, CHUNKS), 256, 0, stream>>>(R, s0, yeh, Ebuf, out, T, B, Gc);
}